// Round 7
// baseline (212.091 us; speedup 1.0000x reference)
//
#include <hip/hip_runtime.h>
#include <math.h>

#define NEG_SLOPE 0.2f

typedef __attribute__((ext_vector_type(8))) short short8;
typedef __attribute__((ext_vector_type(4))) float f32x4;

static __device__ __forceinline__ float lrelu(float t) { return t > 0.f ? t : NEG_SLOPE * t; }
static __device__ __forceinline__ float bf2f(unsigned short h) {
  union { unsigned int i; float f; } c; c.i = ((unsigned int)h) << 16; return c.f;
}
static __device__ __forceinline__ unsigned short f2bf(float x) {
  union { float f; unsigned int i; } c; c.f = x;
  unsigned int r = (c.i + 0x7fffu + ((c.i >> 16) & 1u)) >> 16;
  return (unsigned short)r;
}
static __device__ __forceinline__ void unpack8(uint4 u, float* f) {
  unsigned int d[4] = {u.x, u.y, u.z, u.w};
#pragma unroll
  for (int i = 0; i < 4; ++i) {
    union { unsigned int i_; float f_; } lo, hi;
    lo.i_ = d[i] << 16;
    hi.i_ = d[i] & 0xffff0000u;
    f[2 * i] = lo.f_;
    f[2 * i + 1] = hi.f_;
  }
}

// ---------------- CSR build (real edges only; self-loops handled in gat kernels) ----------------
__global__ void k_hist(const int* __restrict__ dstI, int* deg, int e) {
  int i = blockIdx.x * 256 + threadIdx.x;
  if (i < e) atomicAdd(&deg[dstI[i]], 1);
}

__global__ __launch_bounds__(256) void k_scan1(const int* __restrict__ deg, int* bsum, int n) {
  int i = blockIdx.x * 256 + threadIdx.x;
  int v = (i < n) ? deg[i] : 0;
#pragma unroll
  for (int off = 32; off; off >>= 1) v += __shfl_xor(v, off, 64);
  __shared__ int ws4[4];
  if ((threadIdx.x & 63) == 0) ws4[threadIdx.x >> 6] = v;
  __syncthreads();
  if (threadIdx.x == 0) bsum[blockIdx.x] = ws4[0] + ws4[1] + ws4[2] + ws4[3];
}

__global__ __launch_bounds__(256) void k_scan2(int* bsum, int nb) {
  __shared__ int s[256];
  int t = threadIdx.x;
  int v = (t < nb) ? bsum[t] : 0;
  s[t] = v;
  __syncthreads();
  for (int off = 1; off < 256; off <<= 1) {
    int u = (t >= off) ? s[t - off] : 0;
    __syncthreads();
    s[t] += u;
    __syncthreads();
  }
  if (t < nb) bsum[t] = s[t] - v;  // exclusive
}

__global__ __launch_bounds__(256) void k_scan3(const int* __restrict__ deg, const int* __restrict__ bsum,
                                               int* offs, int* cur, int n, int total) {
  __shared__ int s[256];
  int t = threadIdx.x;
  int i = blockIdx.x * 256 + t;
  int v = (i < n) ? deg[i] : 0;
  s[t] = v;
  __syncthreads();
  for (int off = 1; off < 256; off <<= 1) {
    int u = (t >= off) ? s[t - off] : 0;
    __syncthreads();
    s[t] += u;
    __syncthreads();
  }
  if (i < n) {
    int ex = s[t] - v + bsum[blockIdx.x];
    offs[i] = ex;
    cur[i] = ex;
  }
  if (i == 0) offs[n] = total;
}

// XCD-partitioned scatter (bid%8 partition over dst ranges) — csr lines stay XCD-local.
__global__ __launch_bounds__(256) void k_scatter(const int* __restrict__ srcI, const int* __restrict__ dstI,
                                                 int* cur, int* csr, int e, float invp) {
  const int p = blockIdx.x & 7;
  const int s = blockIdx.x >> 3;
  const int NSL = gridDim.x >> 3;
  int chunk = (e + NSL - 1) / NSL;
  int lo = s * chunk;
  int hi = lo + chunk; if (hi > e) hi = e;
  for (int i = lo + threadIdx.x; i < hi; i += 256) {
    int d = dstI[i];
    int pd = (int)((float)d * invp); pd = pd > 7 ? 7 : pd;
    if (pd == p) {
      int pos = atomicAdd(&cur[d], 1);
      csr[pos] = srcI[i];
    }
  }
}

// ---------------- W transpose + split-bf16 convert ----------------
__global__ __launch_bounds__(256) void k_cvtW(const float* __restrict__ Wl, const float* __restrict__ Wr,
                                              unsigned short* __restrict__ Wth,
                                              unsigned short* __restrict__ Wtl) {
  int tid = blockIdx.x * 256 + threadIdx.x;   // [0, 32768)
  int wsel = tid >> 14;
  int rem = tid & 16383;
  int k = rem >> 7, c = rem & 127;
  float v = wsel ? Wr[k * 128 + c] : Wl[k * 128 + c];
  unsigned short h = f2bf(v);
  unsigned short lo = f2bf(v - bf2f(h));
  Wth[(c + 128 * wsel) * 128 + k] = h;
  Wtl[(c + 128 * wsel) * 128 + k] = lo;
}

// ---------------- split-bf16 MFMA GEMM -> packed bf16 xlr[N][256] (cols 0-127 xl, 128-255 xr) ----------------
__global__ __launch_bounds__(256) void k_mfma(const float* __restrict__ X,
                                              const unsigned short* __restrict__ Wth,
                                              const unsigned short* __restrict__ Wtl,
                                              const float* __restrict__ bl, const float* __restrict__ br,
                                              unsigned short* __restrict__ xlr, int n) {
  __shared__ __align__(16) char lds[40960];
  char* wh = lds;            // 16 KB: [256 col][32 k] bf16 hi, 16B-slot swizzled
  char* wlo = lds + 16384;   // 16 KB: lo
  char* xh = lds + 32768;    //  4 KB: [64 row][32 k] bf16 hi
  char* xo = lds + 36864;    //  4 KB: lo
  const int t = threadIdx.x;
  const int w = t >> 6, l = t & 63;
  const int lr = l & 15, lg = l >> 4;
  const int R0 = blockIdx.x * 64;

  f32x4 acc[4][4];
#pragma unroll
  for (int m = 0; m < 4; ++m)
#pragma unroll
    for (int nn = 0; nn < 4; ++nn) acc[m][nn] = (f32x4)(0.f);

  for (int k0 = 0; k0 < 128; k0 += 32) {
    if (k0) __syncthreads();
#pragma unroll
    for (int i = 0; i < 4; ++i) {
      int flat = t + i * 256;
      int col = flat >> 2, kc = flat & 3;
      int sw = (col & 3) ^ ((col >> 2) & 3);
      int off = col * 64 + ((kc ^ sw) << 4);
      *(uint4*)(wh + off) = *(const uint4*)(Wth + col * 128 + k0 + kc * 8);
      *(uint4*)(wlo + off) = *(const uint4*)(Wtl + col * 128 + k0 + kc * 8);
    }
    {
      int row = t >> 2, kc = t & 3;
      int r = R0 + row;
      float4 v0 = make_float4(0.f, 0.f, 0.f, 0.f), v1 = v0;
      if (r < n) {
        const float* p = X + (size_t)r * 128 + k0 + kc * 8;
        v0 = *(const float4*)p;
        v1 = *(const float4*)(p + 4);
      }
      float xs[8] = {v0.x, v0.y, v0.z, v0.w, v1.x, v1.y, v1.z, v1.w};
      unsigned int hi[4], lo[4];
#pragma unroll
      for (int i = 0; i < 4; ++i) {
        unsigned short h0 = f2bf(xs[2 * i]), h1 = f2bf(xs[2 * i + 1]);
        unsigned short l0 = f2bf(xs[2 * i] - bf2f(h0)), l1 = f2bf(xs[2 * i + 1] - bf2f(h1));
        hi[i] = (unsigned int)h0 | ((unsigned int)h1 << 16);
        lo[i] = (unsigned int)l0 | ((unsigned int)l1 << 16);
      }
      int sw = (row & 3) ^ ((row >> 2) & 3);
      int off = row * 64 + ((kc ^ sw) << 4);
      *(uint4*)(xh + off) = make_uint4(hi[0], hi[1], hi[2], hi[3]);
      *(uint4*)(xo + off) = make_uint4(lo[0], lo[1], lo[2], lo[3]);
    }
    __syncthreads();
    short8 axh[4], axl[4];
#pragma unroll
    for (int m = 0; m < 4; ++m) {
      int row = m * 16 + lr;
      int sw = (row & 3) ^ ((row >> 2) & 3);
      int off = row * 64 + ((lg ^ sw) << 4);
      axh[m] = *(const short8*)(xh + off);
      axl[m] = *(const short8*)(xo + off);
    }
#pragma unroll
    for (int nn = 0; nn < 4; ++nn) {
      int col = w * 64 + nn * 16 + lr;
      int sw = (col & 3) ^ ((col >> 2) & 3);
      int off = col * 64 + ((lg ^ sw) << 4);
      short8 bh = *(const short8*)(wh + off);
      short8 bo = *(const short8*)(wlo + off);
#pragma unroll
      for (int m = 0; m < 4; ++m) {
        acc[m][nn] = __builtin_amdgcn_mfma_f32_16x16x32_bf16(bh, axh[m], acc[m][nn], 0, 0, 0);
        acc[m][nn] = __builtin_amdgcn_mfma_f32_16x16x32_bf16(bh, axl[m], acc[m][nn], 0, 0, 0);
        acc[m][nn] = __builtin_amdgcn_mfma_f32_16x16x32_bf16(bo, axh[m], acc[m][nn], 0, 0, 0);
      }
    }
  }
  // epilogue: bias + single bf16 round, direct 8-B stores
#pragma unroll
  for (int nn = 0; nn < 4; ++nn) {
    int colb = w * 64 + nn * 16 + lg * 4;
    const float* bp = (colb < 128) ? bl : br;
    float4 bv = *(const float4*)(bp + (colb & 127));
#pragma unroll
    for (int m = 0; m < 4; ++m) {
      int row = R0 + m * 16 + lr;
      if (row < n) {
        f32x4 o = acc[m][nn];
        uint2 pk;
        pk.x = (unsigned int)f2bf(o[0] + bv.x) | ((unsigned int)f2bf(o[1] + bv.y) << 16);
        pk.y = (unsigned int)f2bf(o[2] + bv.z) | ((unsigned int)f2bf(o[3] + bv.w) << 16);
        *(uint2*)(xlr + (size_t)row * 256 + colb) = pk;
      }
    }
  }
}

// ---------------- layer-1 GATv2: wave per dst, 8 edge-groups x 8 lanes, prefetched bf16 gathers ----------------
__global__ __launch_bounds__(256) void k_gat1(const unsigned short* __restrict__ xlr,
                                              const float* __restrict__ att, const float* __restrict__ bias,
                                              const float* __restrict__ W2l, const float* __restrict__ b2l,
                                              const float* __restrict__ W2r, const float* __restrict__ b2r,
                                              const int* __restrict__ offs, const int* __restrict__ csr,
                                              float* __restrict__ hl, float* __restrict__ hr, int n) {
  int wave = (blockIdx.x * 256 + threadIdx.x) >> 6;
  int lane = threadIdx.x & 63;
  if (wave >= n) return;
  const int v = wave;
  const int g = lane >> 3;   // edge group 0..7
  const int q = lane & 7;    // channel octet: ch q*16 .. q*16+15
  const int cb = q * 16;

  const unsigned short* xrp = xlr + (size_t)v * 256 + 128 + cb;
  float xrf[16];
  unpack8(*(const uint4*)xrp, xrf);
  unpack8(*(const uint4*)(xrp + 8), xrf + 8);
  float av[16];
#pragma unroll
  for (int i = 0; i < 16; ++i) av[i] = att[cb + i];

  float acc[16];
#pragma unroll
  for (int i = 0; i < 16; ++i) acc[i] = 0.f;
  float denom = 0.f;
  const int s0 = offs[v], s1 = offs[v + 1];

  // self-loop (group 0 only)
  if (g == 0) {
    const unsigned short* sp = xlr + (size_t)v * 256 + cb;
    float xf[16];
    unpack8(*(const uint4*)sp, xf);
    unpack8(*(const uint4*)(sp + 8), xf + 8);
    float p = 0.f;
#pragma unroll
    for (int i = 0; i < 16; ++i) p += lrelu(xf[i] + xrf[i]) * av[i];
    p += __shfl_xor(p, 1, 64);
    p += __shfl_xor(p, 2, 64);
    p += __shfl_xor(p, 4, 64);
    float pe = __expf(p);
    denom += pe;
#pragma unroll
    for (int i = 0; i < 16; ++i) acc[i] += pe * xf[i];
  }

  int j = s0 + g;
  int sN = (j < s1) ? csr[j] : 0;
  const unsigned short* pN = xlr + (size_t)sN * 256 + cb;
  uint4 n0 = *(const uint4*)pN;
  uint4 n1 = *(const uint4*)(pN + 8);
  for (; j < s1; j += 8) {
    uint4 c0 = n0, c1 = n1;
    int jn = j + 8;
    sN = (jn < s1) ? csr[jn] : 0;
    pN = xlr + (size_t)sN * 256 + cb;
    n0 = *(const uint4*)pN;
    n1 = *(const uint4*)(pN + 8);
    float xf[16];
    unpack8(c0, xf);
    unpack8(c1, xf + 8);
    float p = 0.f;
#pragma unroll
    for (int i = 0; i < 16; ++i) p += lrelu(xf[i] + xrf[i]) * av[i];
    p += __shfl_xor(p, 1, 64);
    p += __shfl_xor(p, 2, 64);
    p += __shfl_xor(p, 4, 64);
    float pe = __expf(p);  // |p| bounded small: no max-subtraction needed
    denom += pe;
#pragma unroll
    for (int i = 0; i < 16; ++i) acc[i] += pe * xf[i];
  }
  // cross-group reduce (xor 8,16,32)
#pragma unroll
  for (int off = 8; off <= 32; off <<= 1) {
#pragma unroll
    for (int i = 0; i < 16; ++i) acc[i] += __shfl_xor(acc[i], off, 64);
    denom += __shfl_xor(denom, off, 64);
  }
  float inv = 1.f / denom;
  float pl = 0.f, pr = 0.f;
#pragma unroll
  for (int i = 0; i < 16; ++i) {
    float h = fmaxf(acc[i] * inv + bias[cb + i], 0.f);  // + relu
    pl += h * W2l[cb + i];
    pr += h * W2r[cb + i];
  }
#pragma unroll
  for (int off = 1; off <= 4; off <<= 1) {
    pl += __shfl_xor(pl, off, 64);
    pr += __shfl_xor(pr, off, 64);
  }
  if (lane == 0) {
    hl[v] = pl + b2l[0];
    hr[v] = pr + b2r[0];
  }
}

// ---------------- layer-2 GATv2 (scalar) + sigmoid; self-loop on lane 0 ----------------
__global__ __launch_bounds__(256) void k_gat2(const float* __restrict__ hl, const float* __restrict__ hr,
                                              const float* __restrict__ att2, const float* __restrict__ bias2,
                                              const int* __restrict__ offs, const int* __restrict__ csr,
                                              float* __restrict__ out, int n) {
  int wave = (blockIdx.x * 256 + threadIdx.x) >> 6;
  int lane = threadIdx.x & 63;
  if (wave >= n) return;
  const int v = wave;
  const float a2 = att2[0];
  const float hrv = hr[v];
  float d = 0.f, num = 0.f;
  if (lane == 0) {  // self-loop
    float hlv = hl[v];
    float pe = __expf(a2 * lrelu(hlv + hrv));
    d += pe;
    num += pe * hlv;
  }
  const int s0 = offs[v], s1 = offs[v + 1];
  for (int j = s0 + lane; j < s1; j += 64) {
    int s = csr[j];
    float hls = hl[s];
    float pe = __expf(a2 * lrelu(hls + hrv));
    d += pe;
    num += pe * hls;
  }
#pragma unroll
  for (int off = 32; off; off >>= 1) {
    d += __shfl_xor(d, off, 64);
    num += __shfl_xor(num, off, 64);
  }
  if (lane == 0) {
    float z = num / d + bias2[0];
    float o = 1.f / (1.f + __expf(-z));
    out[v] = o;
    out[n + v] = o;
    out[2 * n + v] = o;
  }
}

extern "C" void kernel_launch(void* const* d_in, const int* in_sizes, int n_in,
                              void* d_out, int out_size, void* d_ws, size_t ws_size,
                              hipStream_t stream) {
  const float* x     = (const float*)d_in[0];
  const int*   ei    = (const int*)d_in[1];
  const float* W1l   = (const float*)d_in[2];
  const float* b1l   = (const float*)d_in[3];
  const float* W1r   = (const float*)d_in[4];
  const float* b1r   = (const float*)d_in[5];
  const float* att1  = (const float*)d_in[6];
  const float* bias1 = (const float*)d_in[7];
  const float* W2l   = (const float*)d_in[8];
  const float* b2l   = (const float*)d_in[9];
  const float* W2r   = (const float*)d_in[10];
  const float* b2r   = (const float*)d_in[11];
  const float* att2  = (const float*)d_in[12];
  const float* bias2 = (const float*)d_in[13];
  float* out = (float*)d_out;

  const int N = in_sizes[0] / 128;
  const int E = in_sizes[1] / 2;
  const int* srcI = ei;
  const int* dstI = ei + E;

  // workspace carve (256-B aligned)
  char* w = (char*)d_ws;
  auto alloc = [&](size_t bytes) {
    char* p = w;
    w += (bytes + 255) & ~(size_t)255;
    return p;
  };
  int* deg   = (int*)alloc((size_t)N * 4);
  int* bsum  = (int*)alloc(1024);
  int* offs  = (int*)alloc((size_t)(N + 1) * 4);
  int* cur   = (int*)alloc((size_t)N * 4);
  int* csr   = (int*)alloc((size_t)E * 4);
  unsigned short* Wth = (unsigned short*)alloc(256 * 128 * 2);
  unsigned short* Wtl = (unsigned short*)alloc(256 * 128 * 2);
  unsigned short* xlr = (unsigned short*)alloc((size_t)N * 256 * 2);
  float* hl  = (float*)alloc((size_t)N * 4);
  float* hr  = (float*)alloc((size_t)N * 4);

  const int NB = (N + 255) / 256;

  hipMemsetAsync(deg, 0, (size_t)N * 4, stream);
  k_cvtW<<<128, 256, 0, stream>>>(W1l, W1r, Wth, Wtl);
  k_hist<<<(E + 255) / 256, 256, 0, stream>>>(dstI, deg, E);
  k_scan1<<<NB, 256, 0, stream>>>(deg, bsum, N);
  k_scan2<<<1, 256, 0, stream>>>(bsum, NB);
  k_scan3<<<NB, 256, 0, stream>>>(deg, bsum, offs, cur, N, E);

  const float invp = 8.0f / (float)N;
  k_scatter<<<1024, 256, 0, stream>>>(srcI, dstI, cur, csr, E, invp);

  const int LB = (N + 63) / 64;
  k_mfma<<<LB, 256, 0, stream>>>(x, Wth, Wtl, b1l, b1r, xlr, N);

  const int GB = (N + 3) / 4;  // 4 waves (nodes) per 256-thread block
  k_gat1<<<GB, 256, 0, stream>>>(xlr, att1, bias1, W2l, b2l, W2r, b2r, offs, csr, hl, hr, N);
  k_gat2<<<GB, 256, 0, stream>>>(hl, hr, att2, bias2, offs, csr, out, N);
}

// Round 8
// 184.527 us; speedup vs baseline: 1.1494x; 1.1494x over previous
//
#include <hip/hip_runtime.h>
#include <math.h>

#define NEG_SLOPE 0.2f

typedef __attribute__((ext_vector_type(8))) short short8;
typedef __attribute__((ext_vector_type(4))) float f32x4;

static __device__ __forceinline__ float lrelu(float t) { return t > 0.f ? t : NEG_SLOPE * t; }
static __device__ __forceinline__ float bf2f(unsigned short h) {
  union { unsigned int i; float f; } c; c.i = ((unsigned int)h) << 16; return c.f;
}
static __device__ __forceinline__ unsigned short f2bf(float x) {
  union { float f; unsigned int i; } c; c.f = x;
  unsigned int r = (c.i + 0x7fffu + ((c.i >> 16) & 1u)) >> 16;
  return (unsigned short)r;
}
static __device__ __forceinline__ void unpack8(uint4 u, float* f) {
  unsigned int d[4] = {u.x, u.y, u.z, u.w};
#pragma unroll
  for (int i = 0; i < 4; ++i) {
    union { unsigned int i_; float f_; } lo, hi;
    lo.i_ = d[i] << 16;
    hi.i_ = d[i] & 0xffff0000u;
    f[2 * i] = lo.f_;
    f[2 * i + 1] = hi.f_;
  }
}

// ---------------- CSR build (real edges only; self-loops handled in gat kernels) ----------------
__global__ void k_hist(const int* __restrict__ dstI, int* deg, int e) {
  int i = blockIdx.x * 256 + threadIdx.x;
  if (i < e) atomicAdd(&deg[dstI[i]], 1);
}

__global__ __launch_bounds__(256) void k_scan1(const int* __restrict__ deg, int* bsum, int n) {
  int i = blockIdx.x * 256 + threadIdx.x;
  int v = (i < n) ? deg[i] : 0;
#pragma unroll
  for (int off = 32; off; off >>= 1) v += __shfl_xor(v, off, 64);
  __shared__ int ws4[4];
  if ((threadIdx.x & 63) == 0) ws4[threadIdx.x >> 6] = v;
  __syncthreads();
  if (threadIdx.x == 0) bsum[blockIdx.x] = ws4[0] + ws4[1] + ws4[2] + ws4[3];
}

__global__ __launch_bounds__(256) void k_scan2(int* bsum, int nb) {
  __shared__ int s[256];
  int t = threadIdx.x;
  int v = (t < nb) ? bsum[t] : 0;
  s[t] = v;
  __syncthreads();
  for (int off = 1; off < 256; off <<= 1) {
    int u = (t >= off) ? s[t - off] : 0;
    __syncthreads();
    s[t] += u;
    __syncthreads();
  }
  if (t < nb) bsum[t] = s[t] - v;  // exclusive
}

__global__ __launch_bounds__(256) void k_scan3(const int* __restrict__ deg, const int* __restrict__ bsum,
                                               int* offs, int* cur, int n, int total) {
  __shared__ int s[256];
  int t = threadIdx.x;
  int i = blockIdx.x * 256 + t;
  int v = (i < n) ? deg[i] : 0;
  s[t] = v;
  __syncthreads();
  for (int off = 1; off < 256; off <<= 1) {
    int u = (t >= off) ? s[t - off] : 0;
    __syncthreads();
    s[t] += u;
    __syncthreads();
  }
  if (i < n) {
    int ex = s[t] - v + bsum[blockIdx.x];
    offs[i] = ex;
    cur[i] = ex;
  }
  if (i == 0) offs[n] = total;
}

// XCD-partitioned scatter (bid%8 partition over dst ranges) — csr lines stay XCD-local.
__global__ __launch_bounds__(256) void k_scatter(const int* __restrict__ srcI, const int* __restrict__ dstI,
                                                 int* cur, int* csr, int e, float invp) {
  const int p = blockIdx.x & 7;
  const int s = blockIdx.x >> 3;
  const int NSL = gridDim.x >> 3;
  int chunk = (e + NSL - 1) / NSL;
  int lo = s * chunk;
  int hi = lo + chunk; if (hi > e) hi = e;
  for (int i = lo + threadIdx.x; i < hi; i += 256) {
    int d = dstI[i];
    int pd = (int)((float)d * invp); pd = pd > 7 ? 7 : pd;
    if (pd == p) {
      int pos = atomicAdd(&cur[d], 1);
      csr[pos] = srcI[i];
    }
  }
}

// ---------------- W transpose + split-bf16 convert ----------------
__global__ __launch_bounds__(256) void k_cvtW(const float* __restrict__ Wl, const float* __restrict__ Wr,
                                              unsigned short* __restrict__ Wth,
                                              unsigned short* __restrict__ Wtl) {
  int tid = blockIdx.x * 256 + threadIdx.x;   // [0, 32768)
  int wsel = tid >> 14;
  int rem = tid & 16383;
  int k = rem >> 7, c = rem & 127;
  float v = wsel ? Wr[k * 128 + c] : Wl[k * 128 + c];
  unsigned short h = f2bf(v);
  unsigned short lo = f2bf(v - bf2f(h));
  Wth[(c + 128 * wsel) * 128 + k] = h;
  Wtl[(c + 128 * wsel) * 128 + k] = lo;
}

// ---------------- split-bf16 MFMA GEMM -> packed bf16 xlr[N][256] (cols 0-127 xl, 128-255 xr) ----------------
__global__ __launch_bounds__(256) void k_mfma(const float* __restrict__ X,
                                              const unsigned short* __restrict__ Wth,
                                              const unsigned short* __restrict__ Wtl,
                                              const float* __restrict__ bl, const float* __restrict__ br,
                                              unsigned short* __restrict__ xlr, int n) {
  __shared__ __align__(16) char lds[40960];
  char* wh = lds;            // 16 KB: [256 col][32 k] bf16 hi, 16B-slot swizzled
  char* wlo = lds + 16384;   // 16 KB: lo
  char* xh = lds + 32768;    //  4 KB: [64 row][32 k] bf16 hi
  char* xo = lds + 36864;    //  4 KB: lo
  const int t = threadIdx.x;
  const int w = t >> 6, l = t & 63;
  const int lr = l & 15, lg = l >> 4;
  const int R0 = blockIdx.x * 64;

  f32x4 acc[4][4];
#pragma unroll
  for (int m = 0; m < 4; ++m)
#pragma unroll
    for (int nn = 0; nn < 4; ++nn) acc[m][nn] = (f32x4)(0.f);

  for (int k0 = 0; k0 < 128; k0 += 32) {
    if (k0) __syncthreads();
#pragma unroll
    for (int i = 0; i < 4; ++i) {
      int flat = t + i * 256;
      int col = flat >> 2, kc = flat & 3;
      int sw = (col & 3) ^ ((col >> 2) & 3);
      int off = col * 64 + ((kc ^ sw) << 4);
      *(uint4*)(wh + off) = *(const uint4*)(Wth + col * 128 + k0 + kc * 8);
      *(uint4*)(wlo + off) = *(const uint4*)(Wtl + col * 128 + k0 + kc * 8);
    }
    {
      int row = t >> 2, kc = t & 3;
      int r = R0 + row;
      float4 v0 = make_float4(0.f, 0.f, 0.f, 0.f), v1 = v0;
      if (r < n) {
        const float* p = X + (size_t)r * 128 + k0 + kc * 8;
        v0 = *(const float4*)p;
        v1 = *(const float4*)(p + 4);
      }
      float xs[8] = {v0.x, v0.y, v0.z, v0.w, v1.x, v1.y, v1.z, v1.w};
      unsigned int hi[4], lo[4];
#pragma unroll
      for (int i = 0; i < 4; ++i) {
        unsigned short h0 = f2bf(xs[2 * i]), h1 = f2bf(xs[2 * i + 1]);
        unsigned short l0 = f2bf(xs[2 * i] - bf2f(h0)), l1 = f2bf(xs[2 * i + 1] - bf2f(h1));
        hi[i] = (unsigned int)h0 | ((unsigned int)h1 << 16);
        lo[i] = (unsigned int)l0 | ((unsigned int)l1 << 16);
      }
      int sw = (row & 3) ^ ((row >> 2) & 3);
      int off = row * 64 + ((kc ^ sw) << 4);
      *(uint4*)(xh + off) = make_uint4(hi[0], hi[1], hi[2], hi[3]);
      *(uint4*)(xo + off) = make_uint4(lo[0], lo[1], lo[2], lo[3]);
    }
    __syncthreads();
    short8 axh[4], axl[4];
#pragma unroll
    for (int m = 0; m < 4; ++m) {
      int row = m * 16 + lr;
      int sw = (row & 3) ^ ((row >> 2) & 3);
      int off = row * 64 + ((lg ^ sw) << 4);
      axh[m] = *(const short8*)(xh + off);
      axl[m] = *(const short8*)(xo + off);
    }
#pragma unroll
    for (int nn = 0; nn < 4; ++nn) {
      int col = w * 64 + nn * 16 + lr;
      int sw = (col & 3) ^ ((col >> 2) & 3);
      int off = col * 64 + ((lg ^ sw) << 4);
      short8 bh = *(const short8*)(wh + off);
      short8 bo = *(const short8*)(wlo + off);
#pragma unroll
      for (int m = 0; m < 4; ++m) {
        acc[m][nn] = __builtin_amdgcn_mfma_f32_16x16x32_bf16(bh, axh[m], acc[m][nn], 0, 0, 0);
        acc[m][nn] = __builtin_amdgcn_mfma_f32_16x16x32_bf16(bh, axl[m], acc[m][nn], 0, 0, 0);
        acc[m][nn] = __builtin_amdgcn_mfma_f32_16x16x32_bf16(bo, axh[m], acc[m][nn], 0, 0, 0);
      }
    }
  }
  // epilogue: bias + single bf16 round, direct 8-B stores
#pragma unroll
  for (int nn = 0; nn < 4; ++nn) {
    int colb = w * 64 + nn * 16 + lg * 4;
    const float* bp = (colb < 128) ? bl : br;
    float4 bv = *(const float4*)(bp + (colb & 127));
#pragma unroll
    for (int m = 0; m < 4; ++m) {
      int row = R0 + m * 16 + lr;
      if (row < n) {
        f32x4 o = acc[m][nn];
        uint2 pk;
        pk.x = (unsigned int)f2bf(o[0] + bv.x) | ((unsigned int)f2bf(o[1] + bv.y) << 16);
        pk.y = (unsigned int)f2bf(o[2] + bv.z) | ((unsigned int)f2bf(o[3] + bv.w) << 16);
        *(uint2*)(xlr + (size_t)row * 256 + colb) = pk;
      }
    }
  }
}

// ---------------- layer-1 GATv2: wave per dst, 4 edge-groups x 16 lanes, bf16 gathers ----------------
__global__ __launch_bounds__(256) void k_gat1(const unsigned short* __restrict__ xlr,
                                              const float* __restrict__ att, const float* __restrict__ bias,
                                              const float* __restrict__ W2l, const float* __restrict__ b2l,
                                              const float* __restrict__ W2r, const float* __restrict__ b2r,
                                              const int* __restrict__ offs, const int* __restrict__ csr,
                                              float* __restrict__ hl, float* __restrict__ hr, int n) {
  int wave = (blockIdx.x * 256 + threadIdx.x) >> 6;
  int lane = threadIdx.x & 63;
  if (wave >= n) return;
  const int v = wave;
  const int g = lane >> 4;   // edge group 0..3
  const int q = lane & 15;   // channel octet: ch q*8 .. q*8+7
  const int cb = q * 8;

  float xrf[8];
  unpack8(*(const uint4*)(xlr + (size_t)v * 256 + 128 + cb), xrf);
  float av[8];
#pragma unroll
  for (int i = 0; i < 8; ++i) av[i] = att[cb + i];

  float acc[8] = {0.f, 0.f, 0.f, 0.f, 0.f, 0.f, 0.f, 0.f};
  float denom = 0.f;
  const int s0 = offs[v], s1 = offs[v + 1];

  // self-loop (group 0 only)
  if (g == 0) {
    float xf[8];
    unpack8(*(const uint4*)(xlr + (size_t)v * 256 + cb), xf);
    float p = 0.f;
#pragma unroll
    for (int i = 0; i < 8; ++i) p += lrelu(xf[i] + xrf[i]) * av[i];
    p += __shfl_xor(p, 1, 64);
    p += __shfl_xor(p, 2, 64);
    p += __shfl_xor(p, 4, 64);
    p += __shfl_xor(p, 8, 64);
    float pe = __expf(p);
    denom += pe;
#pragma unroll
    for (int i = 0; i < 8; ++i) acc[i] += pe * xf[i];
  }

  for (int j = s0 + g; j < s1; j += 4) {
    int s = csr[j];
    float xf[8];
    unpack8(*(const uint4*)(xlr + (size_t)s * 256 + cb), xf);
    float p = 0.f;
#pragma unroll
    for (int i = 0; i < 8; ++i) p += lrelu(xf[i] + xrf[i]) * av[i];
    p += __shfl_xor(p, 1, 64);
    p += __shfl_xor(p, 2, 64);
    p += __shfl_xor(p, 4, 64);
    p += __shfl_xor(p, 8, 64);
    float pe = __expf(p);  // |p| bounded small: no max-subtraction needed
    denom += pe;
#pragma unroll
    for (int i = 0; i < 8; ++i) acc[i] += pe * xf[i];
  }
  // cross-group reduce (xor 16, 32)
#pragma unroll
  for (int off = 16; off <= 32; off <<= 1) {
#pragma unroll
    for (int i = 0; i < 8; ++i) acc[i] += __shfl_xor(acc[i], off, 64);
    denom += __shfl_xor(denom, off, 64);
  }
  float inv = 1.f / denom;
  float pl = 0.f, pr = 0.f;
#pragma unroll
  for (int i = 0; i < 8; ++i) {
    float h = fmaxf(acc[i] * inv + bias[cb + i], 0.f);  // + relu
    pl += h * W2l[cb + i];
    pr += h * W2r[cb + i];
  }
#pragma unroll
  for (int off = 1; off <= 8; off <<= 1) {
    pl += __shfl_xor(pl, off, 64);
    pr += __shfl_xor(pr, off, 64);
  }
  if (lane == 0) {
    hl[v] = pl + b2l[0];
    hr[v] = pr + b2r[0];
  }
}

// ---------------- layer-2 GATv2 (scalar) + sigmoid; self-loop on lane 0 ----------------
__global__ __launch_bounds__(256) void k_gat2(const float* __restrict__ hl, const float* __restrict__ hr,
                                              const float* __restrict__ att2, const float* __restrict__ bias2,
                                              const int* __restrict__ offs, const int* __restrict__ csr,
                                              float* __restrict__ out, int n) {
  int wave = (blockIdx.x * 256 + threadIdx.x) >> 6;
  int lane = threadIdx.x & 63;
  if (wave >= n) return;
  const int v = wave;
  const float a2 = att2[0];
  const float hrv = hr[v];
  float d = 0.f, num = 0.f;
  if (lane == 0) {  // self-loop
    float hlv = hl[v];
    float pe = __expf(a2 * lrelu(hlv + hrv));
    d += pe;
    num += pe * hlv;
  }
  const int s0 = offs[v], s1 = offs[v + 1];
  for (int j = s0 + lane; j < s1; j += 64) {
    int s = csr[j];
    float hls = hl[s];
    float pe = __expf(a2 * lrelu(hls + hrv));
    d += pe;
    num += pe * hls;
  }
#pragma unroll
  for (int off = 32; off; off >>= 1) {
    d += __shfl_xor(d, off, 64);
    num += __shfl_xor(num, off, 64);
  }
  if (lane == 0) {
    float z = num / d + bias2[0];
    float o = 1.f / (1.f + __expf(-z));
    out[v] = o;
    out[n + v] = o;
    out[2 * n + v] = o;
  }
}

extern "C" void kernel_launch(void* const* d_in, const int* in_sizes, int n_in,
                              void* d_out, int out_size, void* d_ws, size_t ws_size,
                              hipStream_t stream) {
  const float* x     = (const float*)d_in[0];
  const int*   ei    = (const int*)d_in[1];
  const float* W1l   = (const float*)d_in[2];
  const float* b1l   = (const float*)d_in[3];
  const float* W1r   = (const float*)d_in[4];
  const float* b1r   = (const float*)d_in[5];
  const float* att1  = (const float*)d_in[6];
  const float* bias1 = (const float*)d_in[7];
  const float* W2l   = (const float*)d_in[8];
  const float* b2l   = (const float*)d_in[9];
  const float* W2r   = (const float*)d_in[10];
  const float* b2r   = (const float*)d_in[11];
  const float* att2  = (const float*)d_in[12];
  const float* bias2 = (const float*)d_in[13];
  float* out = (float*)d_out;

  const int N = in_sizes[0] / 128;
  const int E = in_sizes[1] / 2;
  const int* srcI = ei;
  const int* dstI = ei + E;

  // workspace carve (256-B aligned)
  char* w = (char*)d_ws;
  auto alloc = [&](size_t bytes) {
    char* p = w;
    w += (bytes + 255) & ~(size_t)255;
    return p;
  };
  int* deg   = (int*)alloc((size_t)N * 4);
  int* bsum  = (int*)alloc(1024);
  int* offs  = (int*)alloc((size_t)(N + 1) * 4);
  int* cur   = (int*)alloc((size_t)N * 4);
  int* csr   = (int*)alloc((size_t)E * 4);
  unsigned short* Wth = (unsigned short*)alloc(256 * 128 * 2);
  unsigned short* Wtl = (unsigned short*)alloc(256 * 128 * 2);
  unsigned short* xlr = (unsigned short*)alloc((size_t)N * 256 * 2);
  float* hl  = (float*)alloc((size_t)N * 4);
  float* hr  = (float*)alloc((size_t)N * 4);

  const int NB = (N + 255) / 256;

  hipMemsetAsync(deg, 0, (size_t)N * 4, stream);
  k_cvtW<<<128, 256, 0, stream>>>(W1l, W1r, Wth, Wtl);
  k_hist<<<(E + 255) / 256, 256, 0, stream>>>(dstI, deg, E);
  k_scan1<<<NB, 256, 0, stream>>>(deg, bsum, N);
  k_scan2<<<1, 256, 0, stream>>>(bsum, NB);
  k_scan3<<<NB, 256, 0, stream>>>(deg, bsum, offs, cur, N, E);

  const float invp = 8.0f / (float)N;
  k_scatter<<<1024, 256, 0, stream>>>(srcI, dstI, cur, csr, E, invp);

  const int LB = (N + 63) / 64;
  k_mfma<<<LB, 256, 0, stream>>>(x, Wth, Wtl, b1l, b1r, xlr, N);

  const int GB = (N + 3) / 4;  // 4 waves (nodes) per 256-thread block
  k_gat1<<<GB, 256, 0, stream>>>(xlr, att1, bias1, W2l, b2l, W2r, b2r, offs, csr, hl, hr, N);
  k_gat2<<<GB, 256, 0, stream>>>(hl, hr, att2, bias2, offs, csr, out, N);
}

// Round 9
// 182.119 us; speedup vs baseline: 1.1646x; 1.0132x over previous
//
#include <hip/hip_runtime.h>
#include <math.h>

#define NEG_SLOPE 0.2f

typedef __attribute__((ext_vector_type(8))) short short8;
typedef __attribute__((ext_vector_type(4))) float f32x4;

static __device__ __forceinline__ float lrelu(float t) { return t > 0.f ? t : NEG_SLOPE * t; }
static __device__ __forceinline__ float bf2f(unsigned short h) {
  union { unsigned int i; float f; } c; c.i = ((unsigned int)h) << 16; return c.f;
}
static __device__ __forceinline__ unsigned short f2bf(float x) {
  union { float f; unsigned int i; } c; c.f = x;
  unsigned int r = (c.i + 0x7fffu + ((c.i >> 16) & 1u)) >> 16;
  return (unsigned short)r;
}
static __device__ __forceinline__ void unpack8(uint4 u, float* f) {
  unsigned int d[4] = {u.x, u.y, u.z, u.w};
#pragma unroll
  for (int i = 0; i < 4; ++i) {
    union { unsigned int i_; float f_; } lo, hi;
    lo.i_ = d[i] << 16;
    hi.i_ = d[i] & 0xffff0000u;
    f[2 * i] = lo.f_;
    f[2 * i + 1] = hi.f_;
  }
}

// ---------------- CSR build (real edges only; self-loops handled in gat kernels) ----------------
// XCD-partitioned histogram: deg lines stay XCD-local (no cross-XCD atomic ping-pong).
__global__ __launch_bounds__(256) void k_hist(const int* __restrict__ dstI, int* deg, int e, float invp) {
  const int p = blockIdx.x & 7;
  const int s = blockIdx.x >> 3;
  const int NSL = gridDim.x >> 3;
  int chunk = (e + NSL - 1) / NSL;
  int lo = s * chunk;
  int hi = lo + chunk; if (hi > e) hi = e;
  for (int i = lo + threadIdx.x; i < hi; i += 256) {
    int d = dstI[i];
    int pd = (int)((float)d * invp); pd = pd > 7 ? 7 : pd;
    if (pd == p) atomicAdd(&deg[d], 1);
  }
}

__global__ __launch_bounds__(256) void k_scan1(const int* __restrict__ deg, int* bsum, int n) {
  int i = blockIdx.x * 256 + threadIdx.x;
  int v = (i < n) ? deg[i] : 0;
#pragma unroll
  for (int off = 32; off; off >>= 1) v += __shfl_xor(v, off, 64);
  __shared__ int ws4[4];
  if ((threadIdx.x & 63) == 0) ws4[threadIdx.x >> 6] = v;
  __syncthreads();
  if (threadIdx.x == 0) bsum[blockIdx.x] = ws4[0] + ws4[1] + ws4[2] + ws4[3];
}

__global__ __launch_bounds__(256) void k_scan2(int* bsum, int nb) {
  __shared__ int s[256];
  int t = threadIdx.x;
  int v = (t < nb) ? bsum[t] : 0;
  s[t] = v;
  __syncthreads();
  for (int off = 1; off < 256; off <<= 1) {
    int u = (t >= off) ? s[t - off] : 0;
    __syncthreads();
    s[t] += u;
    __syncthreads();
  }
  if (t < nb) bsum[t] = s[t] - v;  // exclusive
}

__global__ __launch_bounds__(256) void k_scan3(const int* __restrict__ deg, const int* __restrict__ bsum,
                                               int* offs, int* cur, int n, int total) {
  __shared__ int s[256];
  int t = threadIdx.x;
  int i = blockIdx.x * 256 + t;
  int v = (i < n) ? deg[i] : 0;
  s[t] = v;
  __syncthreads();
  for (int off = 1; off < 256; off <<= 1) {
    int u = (t >= off) ? s[t - off] : 0;
    __syncthreads();
    s[t] += u;
    __syncthreads();
  }
  if (i < n) {
    int ex = s[t] - v + bsum[blockIdx.x];
    offs[i] = ex;
    cur[i] = ex;
  }
  if (i == 0) offs[n] = total;
}

// XCD-partitioned scatter (bid%8 partition over dst ranges) — csr lines stay XCD-local.
__global__ __launch_bounds__(256) void k_scatter(const int* __restrict__ srcI, const int* __restrict__ dstI,
                                                 int* cur, int* csr, int e, float invp) {
  const int p = blockIdx.x & 7;
  const int s = blockIdx.x >> 3;
  const int NSL = gridDim.x >> 3;
  int chunk = (e + NSL - 1) / NSL;
  int lo = s * chunk;
  int hi = lo + chunk; if (hi > e) hi = e;
  for (int i = lo + threadIdx.x; i < hi; i += 256) {
    int d = dstI[i];
    int pd = (int)((float)d * invp); pd = pd > 7 ? 7 : pd;
    if (pd == p) {
      int pos = atomicAdd(&cur[d], 1);
      csr[pos] = srcI[i];
    }
  }
}

// ---------------- W transpose + split-bf16 convert ----------------
__global__ __launch_bounds__(256) void k_cvtW(const float* __restrict__ Wl, const float* __restrict__ Wr,
                                              unsigned short* __restrict__ Wth,
                                              unsigned short* __restrict__ Wtl) {
  int tid = blockIdx.x * 256 + threadIdx.x;   // [0, 32768)
  int wsel = tid >> 14;
  int rem = tid & 16383;
  int k = rem >> 7, c = rem & 127;
  float v = wsel ? Wr[k * 128 + c] : Wl[k * 128 + c];
  unsigned short h = f2bf(v);
  unsigned short lo = f2bf(v - bf2f(h));
  Wth[(c + 128 * wsel) * 128 + k] = h;
  Wtl[(c + 128 * wsel) * 128 + k] = lo;
}

// ---------------- split-bf16 MFMA GEMM -> packed bf16 xlr[N][256] + per-node dots dl,dr ----------------
__global__ __launch_bounds__(256) void k_mfma(const float* __restrict__ X,
                                              const unsigned short* __restrict__ Wth,
                                              const unsigned short* __restrict__ Wtl,
                                              const float* __restrict__ bl, const float* __restrict__ br,
                                              const float* __restrict__ att,
                                              unsigned short* __restrict__ xlr,
                                              float* __restrict__ dl, float* __restrict__ dr, int n) {
  __shared__ __align__(16) char lds[40960];
  char* wh = lds;            // 16 KB: [256 col][32 k] bf16 hi, 16B-slot swizzled
  char* wlo = lds + 16384;   // 16 KB: lo
  char* xh = lds + 32768;    //  4 KB: [64 row][32 k] bf16 hi
  char* xo = lds + 36864;    //  4 KB: lo
  const int t = threadIdx.x;
  const int w = t >> 6, l = t & 63;
  const int lr = l & 15, lg = l >> 4;
  const int R0 = blockIdx.x * 64;

  f32x4 acc[4][4];
#pragma unroll
  for (int m = 0; m < 4; ++m)
#pragma unroll
    for (int nn = 0; nn < 4; ++nn) acc[m][nn] = (f32x4)(0.f);

  for (int k0 = 0; k0 < 128; k0 += 32) {
    if (k0) __syncthreads();
#pragma unroll
    for (int i = 0; i < 4; ++i) {
      int flat = t + i * 256;
      int col = flat >> 2, kc = flat & 3;
      int sw = (col & 3) ^ ((col >> 2) & 3);
      int off = col * 64 + ((kc ^ sw) << 4);
      *(uint4*)(wh + off) = *(const uint4*)(Wth + col * 128 + k0 + kc * 8);
      *(uint4*)(wlo + off) = *(const uint4*)(Wtl + col * 128 + k0 + kc * 8);
    }
    {
      int row = t >> 2, kc = t & 3;
      int r = R0 + row;
      float4 v0 = make_float4(0.f, 0.f, 0.f, 0.f), v1 = v0;
      if (r < n) {
        const float* p = X + (size_t)r * 128 + k0 + kc * 8;
        v0 = *(const float4*)p;
        v1 = *(const float4*)(p + 4);
      }
      float xs[8] = {v0.x, v0.y, v0.z, v0.w, v1.x, v1.y, v1.z, v1.w};
      unsigned int hi[4], lo[4];
#pragma unroll
      for (int i = 0; i < 4; ++i) {
        unsigned short h0 = f2bf(xs[2 * i]), h1 = f2bf(xs[2 * i + 1]);
        unsigned short l0 = f2bf(xs[2 * i] - bf2f(h0)), l1 = f2bf(xs[2 * i + 1] - bf2f(h1));
        hi[i] = (unsigned int)h0 | ((unsigned int)h1 << 16);
        lo[i] = (unsigned int)l0 | ((unsigned int)l1 << 16);
      }
      int sw = (row & 3) ^ ((row >> 2) & 3);
      int off = row * 64 + ((kc ^ sw) << 4);
      *(uint4*)(xh + off) = make_uint4(hi[0], hi[1], hi[2], hi[3]);
      *(uint4*)(xo + off) = make_uint4(lo[0], lo[1], lo[2], lo[3]);
    }
    __syncthreads();
    short8 axh[4], axl[4];
#pragma unroll
    for (int m = 0; m < 4; ++m) {
      int row = m * 16 + lr;
      int sw = (row & 3) ^ ((row >> 2) & 3);
      int off = row * 64 + ((lg ^ sw) << 4);
      axh[m] = *(const short8*)(xh + off);
      axl[m] = *(const short8*)(xo + off);
    }
#pragma unroll
    for (int nn = 0; nn < 4; ++nn) {
      int col = w * 64 + nn * 16 + lr;
      int sw = (col & 3) ^ ((col >> 2) & 3);
      int off = col * 64 + ((lg ^ sw) << 4);
      short8 bh = *(const short8*)(wh + off);
      short8 bo = *(const short8*)(wlo + off);
#pragma unroll
      for (int m = 0; m < 4; ++m) {
        acc[m][nn] = __builtin_amdgcn_mfma_f32_16x16x32_bf16(bh, axh[m], acc[m][nn], 0, 0, 0);
        acc[m][nn] = __builtin_amdgcn_mfma_f32_16x16x32_bf16(bh, axl[m], acc[m][nn], 0, 0, 0);
        acc[m][nn] = __builtin_amdgcn_mfma_f32_16x16x32_bf16(bo, axh[m], acc[m][nn], 0, 0, 0);
      }
    }
  }
  // epilogue: bias + bf16 store + per-row att-dot partials
  __syncthreads();  // LDS reuse for the dot reduction
  float* sred = (float*)lds;  // [4 waves][64 rows]
  float part[4];
#pragma unroll
  for (int m = 0; m < 4; ++m) {
    float pm = 0.f;
#pragma unroll
    for (int nn = 0; nn < 4; ++nn) {
      int colb = w * 64 + nn * 16 + lg * 4;
      const float* bp = (colb < 128) ? bl : br;
      float4 bv = *(const float4*)(bp + (colb & 127));
      float4 avv = *(const float4*)(att + (colb & 127));
      f32x4 o = acc[m][nn];
      float v0 = o[0] + bv.x, v1 = o[1] + bv.y, v2 = o[2] + bv.z, v3 = o[3] + bv.w;
      int row = R0 + m * 16 + lr;
      if (row < n) {
        uint2 pk;
        pk.x = (unsigned int)f2bf(v0) | ((unsigned int)f2bf(v1) << 16);
        pk.y = (unsigned int)f2bf(v2) | ((unsigned int)f2bf(v3) << 16);
        *(uint2*)(xlr + (size_t)row * 256 + colb) = pk;
      }
      pm += v0 * avv.x + v1 * avv.y + v2 * avv.z + v3 * avv.w;
    }
    pm += __shfl_xor(pm, 16, 64);
    pm += __shfl_xor(pm, 32, 64);
    part[m] = pm;
  }
  if (lg == 0) {
#pragma unroll
    for (int m = 0; m < 4; ++m) sred[w * 64 + m * 16 + lr] = part[m];
  }
  __syncthreads();
  if (t < 128) {
    int row = t & 63;
    int half = t >> 6;  // 0: l (waves 0,1), 1: r (waves 2,3)
    if (R0 + row < n) {
      float sum = sred[half * 128 + row] + sred[half * 128 + 64 + row];
      (half ? dr : dl)[R0 + row] = sum;
    }
  }
}

// ---------------- layer-1 GATv2: wave per dst, 4 edge-groups x 16 lanes ----------------
// e = 0.6*(dl[s]+dr[v]) + 0.4*sum_c a_c*|xl[s,c]+xr[v,c]|   (leaky = 0.6t + 0.4|t|)
__global__ __launch_bounds__(256) void k_gat1(const unsigned short* __restrict__ xlr,
                                              const float* __restrict__ dl, const float* __restrict__ dr,
                                              const float* __restrict__ att, const float* __restrict__ bias,
                                              const float* __restrict__ W2l, const float* __restrict__ b2l,
                                              const float* __restrict__ W2r, const float* __restrict__ b2r,
                                              const int* __restrict__ offs, const int* __restrict__ csr,
                                              float* __restrict__ hl, float* __restrict__ hr, int n) {
  int wave = (blockIdx.x * 256 + threadIdx.x) >> 6;
  int lane = threadIdx.x & 63;
  if (wave >= n) return;
  const int v = wave;
  const int g = lane >> 4;   // edge group 0..3
  const int q = lane & 15;   // channel octet: ch q*8 .. q*8+7
  const int cb = q * 8;

  float xrf[8];
  unpack8(*(const uint4*)(xlr + (size_t)v * 256 + 128 + cb), xrf);
  float av[8];
#pragma unroll
  for (int i = 0; i < 8; ++i) av[i] = att[cb + i];
  const float c0 = 0.6f * dr[v];  // edge-invariant part of e

  float acc[8] = {0.f, 0.f, 0.f, 0.f, 0.f, 0.f, 0.f, 0.f};
  float denom = 0.f;
  const int s0 = offs[v], s1 = offs[v + 1];

  // self-loop (group 0 only)
  if (g == 0) {
    float dls = dl[v];
    float xf[8];
    unpack8(*(const uint4*)(xlr + (size_t)v * 256 + cb), xf);
    float s2 = 0.f;
#pragma unroll
    for (int i = 0; i < 8; ++i) s2 = fmaf(av[i], fabsf(xf[i] + xrf[i]), s2);
    s2 += __shfl_xor(s2, 1, 64);
    s2 += __shfl_xor(s2, 2, 64);
    s2 += __shfl_xor(s2, 4, 64);
    s2 += __shfl_xor(s2, 8, 64);
    float pe = __expf(fmaf(0.6f, dls, fmaf(0.4f, s2, c0)));
    denom += pe;
#pragma unroll
    for (int i = 0; i < 8; ++i) acc[i] = fmaf(pe, xf[i], acc[i]);
  }

  for (int j = s0 + g; j < s1; j += 4) {
    int s = csr[j];
    float dls = dl[s];
    float xf[8];
    unpack8(*(const uint4*)(xlr + (size_t)s * 256 + cb), xf);
    float s2 = 0.f;
#pragma unroll
    for (int i = 0; i < 8; ++i) s2 = fmaf(av[i], fabsf(xf[i] + xrf[i]), s2);
    s2 += __shfl_xor(s2, 1, 64);
    s2 += __shfl_xor(s2, 2, 64);
    s2 += __shfl_xor(s2, 4, 64);
    s2 += __shfl_xor(s2, 8, 64);
    float pe = __expf(fmaf(0.6f, dls, fmaf(0.4f, s2, c0)));  // |e| small: no max needed
    denom += pe;
#pragma unroll
    for (int i = 0; i < 8; ++i) acc[i] = fmaf(pe, xf[i], acc[i]);
  }
  // cross-group reduce (xor 16, 32)
#pragma unroll
  for (int off = 16; off <= 32; off <<= 1) {
#pragma unroll
    for (int i = 0; i < 8; ++i) acc[i] += __shfl_xor(acc[i], off, 64);
    denom += __shfl_xor(denom, off, 64);
  }
  float inv = 1.f / denom;
  float pl = 0.f, pr = 0.f;
#pragma unroll
  for (int i = 0; i < 8; ++i) {
    float h = fmaxf(acc[i] * inv + bias[cb + i], 0.f);  // + relu
    pl += h * W2l[cb + i];
    pr += h * W2r[cb + i];
  }
#pragma unroll
  for (int off = 1; off <= 8; off <<= 1) {
    pl += __shfl_xor(pl, off, 64);
    pr += __shfl_xor(pr, off, 64);
  }
  if (lane == 0) {
    hl[v] = pl + b2l[0];
    hr[v] = pr + b2r[0];
  }
}

// ---------------- layer-2 GATv2 (scalar) + sigmoid; self-loop on lane 0 ----------------
__global__ __launch_bounds__(256) void k_gat2(const float* __restrict__ hl, const float* __restrict__ hr,
                                              const float* __restrict__ att2, const float* __restrict__ bias2,
                                              const int* __restrict__ offs, const int* __restrict__ csr,
                                              float* __restrict__ out, int n) {
  int wave = (blockIdx.x * 256 + threadIdx.x) >> 6;
  int lane = threadIdx.x & 63;
  if (wave >= n) return;
  const int v = wave;
  const float a2 = att2[0];
  const float hrv = hr[v];
  float d = 0.f, num = 0.f;
  if (lane == 0) {  // self-loop
    float hlv = hl[v];
    float pe = __expf(a2 * lrelu(hlv + hrv));
    d += pe;
    num += pe * hlv;
  }
  const int s0 = offs[v], s1 = offs[v + 1];
  for (int j = s0 + lane; j < s1; j += 64) {
    int s = csr[j];
    float hls = hl[s];
    float pe = __expf(a2 * lrelu(hls + hrv));
    d += pe;
    num += pe * hls;
  }
#pragma unroll
  for (int off = 32; off; off >>= 1) {
    d += __shfl_xor(d, off, 64);
    num += __shfl_xor(num, off, 64);
  }
  if (lane == 0) {
    float z = num / d + bias2[0];
    float o = 1.f / (1.f + __expf(-z));
    out[v] = o;
    out[n + v] = o;
    out[2 * n + v] = o;
  }
}

extern "C" void kernel_launch(void* const* d_in, const int* in_sizes, int n_in,
                              void* d_out, int out_size, void* d_ws, size_t ws_size,
                              hipStream_t stream) {
  const float* x     = (const float*)d_in[0];
  const int*   ei    = (const int*)d_in[1];
  const float* W1l   = (const float*)d_in[2];
  const float* b1l   = (const float*)d_in[3];
  const float* W1r   = (const float*)d_in[4];
  const float* b1r   = (const float*)d_in[5];
  const float* att1  = (const float*)d_in[6];
  const float* bias1 = (const float*)d_in[7];
  const float* W2l   = (const float*)d_in[8];
  const float* b2l   = (const float*)d_in[9];
  const float* W2r   = (const float*)d_in[10];
  const float* b2r   = (const float*)d_in[11];
  const float* att2  = (const float*)d_in[12];
  const float* bias2 = (const float*)d_in[13];
  float* out = (float*)d_out;

  const int N = in_sizes[0] / 128;
  const int E = in_sizes[1] / 2;
  const int* srcI = ei;
  const int* dstI = ei + E;

  // workspace carve (256-B aligned)
  char* w = (char*)d_ws;
  auto alloc = [&](size_t bytes) {
    char* p = w;
    w += (bytes + 255) & ~(size_t)255;
    return p;
  };
  int* deg   = (int*)alloc((size_t)N * 4);
  int* bsum  = (int*)alloc(1024);
  int* offs  = (int*)alloc((size_t)(N + 1) * 4);
  int* cur   = (int*)alloc((size_t)N * 4);
  int* csr   = (int*)alloc((size_t)E * 4);
  unsigned short* Wth = (unsigned short*)alloc(256 * 128 * 2);
  unsigned short* Wtl = (unsigned short*)alloc(256 * 128 * 2);
  unsigned short* xlr = (unsigned short*)alloc((size_t)N * 256 * 2);
  float* dl  = (float*)alloc((size_t)N * 4);
  float* dr  = (float*)alloc((size_t)N * 4);
  float* hl  = (float*)alloc((size_t)N * 4);
  float* hr  = (float*)alloc((size_t)N * 4);

  const int NB = (N + 255) / 256;
  const float invp = 8.0f / (float)N;

  hipMemsetAsync(deg, 0, (size_t)N * 4, stream);
  k_cvtW<<<128, 256, 0, stream>>>(W1l, W1r, Wth, Wtl);
  k_hist<<<1024, 256, 0, stream>>>(dstI, deg, E, invp);
  k_scan1<<<NB, 256, 0, stream>>>(deg, bsum, N);
  k_scan2<<<1, 256, 0, stream>>>(bsum, NB);
  k_scan3<<<NB, 256, 0, stream>>>(deg, bsum, offs, cur, N, E);
  k_scatter<<<1024, 256, 0, stream>>>(srcI, dstI, cur, csr, E, invp);

  const int LB = (N + 63) / 64;
  k_mfma<<<LB, 256, 0, stream>>>(x, Wth, Wtl, b1l, b1r, att1, xlr, dl, dr, N);

  const int GB = (N + 3) / 4;  // 4 waves (nodes) per 256-thread block
  k_gat1<<<GB, 256, 0, stream>>>(xlr, dl, dr, att1, bias1, W2l, b2l, W2r, b2r, offs, csr, hl, hr, N);
  k_gat2<<<GB, 256, 0, stream>>>(hl, hr, att2, bias2, offs, csr, out, N);
}

// Round 10
// 180.124 us; speedup vs baseline: 1.1775x; 1.0111x over previous
//
#include <hip/hip_runtime.h>
#include <math.h>

#define NEG_SLOPE 0.2f

typedef __attribute__((ext_vector_type(8))) short short8;
typedef __attribute__((ext_vector_type(4))) float f32x4;

static __device__ __forceinline__ float lrelu(float t) { return t > 0.f ? t : NEG_SLOPE * t; }
static __device__ __forceinline__ float bf2f(unsigned short h) {
  union { unsigned int i; float f; } c; c.i = ((unsigned int)h) << 16; return c.f;
}
static __device__ __forceinline__ unsigned short f2bf(float x) {
  union { float f; unsigned int i; } c; c.f = x;
  unsigned int r = (c.i + 0x7fffu + ((c.i >> 16) & 1u)) >> 16;
  return (unsigned short)r;
}
static __device__ __forceinline__ void unpack8(uint4 u, float* f) {
  unsigned int d[4] = {u.x, u.y, u.z, u.w};
#pragma unroll
  for (int i = 0; i < 4; ++i) {
    union { unsigned int i_; float f_; } lo, hi;
    lo.i_ = d[i] << 16;
    hi.i_ = d[i] & 0xffff0000u;
    f[2 * i] = lo.f_;
    f[2 * i + 1] = hi.f_;
  }
}

// ---------------- CSR build (real edges only; self-loops handled in gat kernels) ----------------
__global__ void k_hist(const int* __restrict__ dstI, int* deg, int e) {
  int i = blockIdx.x * 256 + threadIdx.x;
  if (i < e) atomicAdd(&deg[dstI[i]], 1);
}

__global__ __launch_bounds__(256) void k_scan1(const int* __restrict__ deg, int* bsum, int n) {
  int i = blockIdx.x * 256 + threadIdx.x;
  int v = (i < n) ? deg[i] : 0;
#pragma unroll
  for (int off = 32; off; off >>= 1) v += __shfl_xor(v, off, 64);
  __shared__ int ws4[4];
  if ((threadIdx.x & 63) == 0) ws4[threadIdx.x >> 6] = v;
  __syncthreads();
  if (threadIdx.x == 0) bsum[blockIdx.x] = ws4[0] + ws4[1] + ws4[2] + ws4[3];
}

// scan3 with inlined bsum-prefix (merges old scan2): each block sums bsum[0..bid)
__global__ __launch_bounds__(256) void k_scan3(const int* __restrict__ deg, const int* __restrict__ bsum,
                                               int* offs, int* cur, int n, int total, int nb) {
  __shared__ int s[256];
  __shared__ int pre4[4];
  int t = threadIdx.x;
  int i = blockIdx.x * 256 + t;
  int b = (t < nb && t < (int)blockIdx.x) ? bsum[t] : 0;
#pragma unroll
  for (int off = 32; off; off >>= 1) b += __shfl_xor(b, off, 64);
  if ((t & 63) == 0) pre4[t >> 6] = b;
  int v = (i < n) ? deg[i] : 0;
  s[t] = v;
  __syncthreads();
  int prefix = pre4[0] + pre4[1] + pre4[2] + pre4[3];
  for (int off = 1; off < 256; off <<= 1) {
    int u = (t >= off) ? s[t - off] : 0;
    __syncthreads();
    s[t] += u;
    __syncthreads();
  }
  if (i < n) {
    int ex = s[t] - v + prefix;
    offs[i] = ex;
    cur[i] = ex;
  }
  if (i == 0) offs[n] = total;
}

// XCD-partitioned scatter (bid%8 partition over dst ranges) — csr lines stay XCD-local.
__global__ __launch_bounds__(256) void k_scatter(const int* __restrict__ srcI, const int* __restrict__ dstI,
                                                 int* cur, int* csr, int e, float invp) {
  const int p = blockIdx.x & 7;
  const int s = blockIdx.x >> 3;
  const int NSL = gridDim.x >> 3;
  int chunk = (e + NSL - 1) / NSL;
  int lo = s * chunk;
  int hi = lo + chunk; if (hi > e) hi = e;
  for (int i = lo + threadIdx.x; i < hi; i += 256) {
    int d = dstI[i];
    int pd = (int)((float)d * invp); pd = pd > 7 ? 7 : pd;
    if (pd == p) {
      int pos = atomicAdd(&cur[d], 1);
      csr[pos] = srcI[i];
    }
  }
}

// ---------------- W transpose + split-bf16 convert; also zeros deg ----------------
__global__ __launch_bounds__(256) void k_cvtW(const float* __restrict__ Wl, const float* __restrict__ Wr,
                                              unsigned short* __restrict__ Wth,
                                              unsigned short* __restrict__ Wtl,
                                              int* __restrict__ deg, int n) {
  int tid = blockIdx.x * 256 + threadIdx.x;   // [0, 32768)
  for (int i = tid; i < n; i += 32768) deg[i] = 0;
  int wsel = tid >> 14;
  int rem = tid & 16383;
  int k = rem >> 7, c = rem & 127;
  float v = wsel ? Wr[k * 128 + c] : Wl[k * 128 + c];
  unsigned short h = f2bf(v);
  unsigned short lo = f2bf(v - bf2f(h));
  Wth[(c + 128 * wsel) * 128 + k] = h;
  Wtl[(c + 128 * wsel) * 128 + k] = lo;
}

// ---------------- split-bf16 MFMA GEMM -> packed bf16 xlr[N][256] + per-node dots 0.6*dl, 0.6*dr ----------------
__global__ __launch_bounds__(256) void k_mfma(const float* __restrict__ X,
                                              const unsigned short* __restrict__ Wth,
                                              const unsigned short* __restrict__ Wtl,
                                              const float* __restrict__ bl, const float* __restrict__ br,
                                              const float* __restrict__ att,
                                              unsigned short* __restrict__ xlr,
                                              float* __restrict__ dl, float* __restrict__ dr, int n) {
  __shared__ __align__(16) char lds[40960];
  char* wh = lds;            // 16 KB: [256 col][32 k] bf16 hi, 16B-slot swizzled
  char* wlo = lds + 16384;   // 16 KB: lo
  char* xh = lds + 32768;    //  4 KB: [64 row][32 k] bf16 hi
  char* xo = lds + 36864;    //  4 KB: lo
  const int t = threadIdx.x;
  const int w = t >> 6, l = t & 63;
  const int lr = l & 15, lg = l >> 4;
  const int R0 = blockIdx.x * 64;

  f32x4 acc[4][4];
#pragma unroll
  for (int m = 0; m < 4; ++m)
#pragma unroll
    for (int nn = 0; nn < 4; ++nn) acc[m][nn] = (f32x4)(0.f);

  for (int k0 = 0; k0 < 128; k0 += 32) {
    if (k0) __syncthreads();
#pragma unroll
    for (int i = 0; i < 4; ++i) {
      int flat = t + i * 256;
      int col = flat >> 2, kc = flat & 3;
      int sw = (col & 3) ^ ((col >> 2) & 3);
      int off = col * 64 + ((kc ^ sw) << 4);
      *(uint4*)(wh + off) = *(const uint4*)(Wth + col * 128 + k0 + kc * 8);
      *(uint4*)(wlo + off) = *(const uint4*)(Wtl + col * 128 + k0 + kc * 8);
    }
    {
      int row = t >> 2, kc = t & 3;
      int r = R0 + row;
      float4 v0 = make_float4(0.f, 0.f, 0.f, 0.f), v1 = v0;
      if (r < n) {
        const float* p = X + (size_t)r * 128 + k0 + kc * 8;
        v0 = *(const float4*)p;
        v1 = *(const float4*)(p + 4);
      }
      float xs[8] = {v0.x, v0.y, v0.z, v0.w, v1.x, v1.y, v1.z, v1.w};
      unsigned int hi[4], lo[4];
#pragma unroll
      for (int i = 0; i < 4; ++i) {
        unsigned short h0 = f2bf(xs[2 * i]), h1 = f2bf(xs[2 * i + 1]);
        unsigned short l0 = f2bf(xs[2 * i] - bf2f(h0)), l1 = f2bf(xs[2 * i + 1] - bf2f(h1));
        hi[i] = (unsigned int)h0 | ((unsigned int)h1 << 16);
        lo[i] = (unsigned int)l0 | ((unsigned int)l1 << 16);
      }
      int sw = (row & 3) ^ ((row >> 2) & 3);
      int off = row * 64 + ((kc ^ sw) << 4);
      *(uint4*)(xh + off) = make_uint4(hi[0], hi[1], hi[2], hi[3]);
      *(uint4*)(xo + off) = make_uint4(lo[0], lo[1], lo[2], lo[3]);
    }
    __syncthreads();
    short8 axh[4], axl[4];
#pragma unroll
    for (int m = 0; m < 4; ++m) {
      int row = m * 16 + lr;
      int sw = (row & 3) ^ ((row >> 2) & 3);
      int off = row * 64 + ((lg ^ sw) << 4);
      axh[m] = *(const short8*)(xh + off);
      axl[m] = *(const short8*)(xo + off);
    }
#pragma unroll
    for (int nn = 0; nn < 4; ++nn) {
      int col = w * 64 + nn * 16 + lr;
      int sw = (col & 3) ^ ((col >> 2) & 3);
      int off = col * 64 + ((lg ^ sw) << 4);
      short8 bh = *(const short8*)(wh + off);
      short8 bo = *(const short8*)(wlo + off);
#pragma unroll
      for (int m = 0; m < 4; ++m) {
        acc[m][nn] = __builtin_amdgcn_mfma_f32_16x16x32_bf16(bh, axh[m], acc[m][nn], 0, 0, 0);
        acc[m][nn] = __builtin_amdgcn_mfma_f32_16x16x32_bf16(bh, axl[m], acc[m][nn], 0, 0, 0);
        acc[m][nn] = __builtin_amdgcn_mfma_f32_16x16x32_bf16(bo, axh[m], acc[m][nn], 0, 0, 0);
      }
    }
  }
  // epilogue: bias + bf16 store + per-row att-dot partials (0.6-prescaled)
  __syncthreads();  // LDS reuse for the dot reduction
  float* sred = (float*)lds;  // [4 waves][64 rows]
  float part[4];
#pragma unroll
  for (int m = 0; m < 4; ++m) {
    float pm = 0.f;
#pragma unroll
    for (int nn = 0; nn < 4; ++nn) {
      int colb = w * 64 + nn * 16 + lg * 4;
      const float* bp = (colb < 128) ? bl : br;
      float4 bv = *(const float4*)(bp + (colb & 127));
      float4 avv = *(const float4*)(att + (colb & 127));
      f32x4 o = acc[m][nn];
      float v0 = o[0] + bv.x, v1 = o[1] + bv.y, v2 = o[2] + bv.z, v3 = o[3] + bv.w;
      int row = R0 + m * 16 + lr;
      if (row < n) {
        uint2 pk;
        pk.x = (unsigned int)f2bf(v0) | ((unsigned int)f2bf(v1) << 16);
        pk.y = (unsigned int)f2bf(v2) | ((unsigned int)f2bf(v3) << 16);
        *(uint2*)(xlr + (size_t)row * 256 + colb) = pk;
      }
      pm += v0 * avv.x + v1 * avv.y + v2 * avv.z + v3 * avv.w;
    }
    pm += __shfl_xor(pm, 16, 64);
    pm += __shfl_xor(pm, 32, 64);
    part[m] = pm;
  }
  if (lg == 0) {
#pragma unroll
    for (int m = 0; m < 4; ++m) sred[w * 64 + m * 16 + lr] = part[m];
  }
  __syncthreads();
  if (t < 128) {
    int row = t & 63;
    int half = t >> 6;  // 0: l (waves 0,1), 1: r (waves 2,3)
    if (R0 + row < n) {
      float sum = sred[half * 128 + row] + sred[half * 128 + 64 + row];
      (half ? dr : dl)[R0 + row] = 0.6f * sum;
    }
  }
}

// ---------------- layer-1 GATv2: wave per dst, 4 edge-groups x 16 lanes, 2-edge unroll ----------------
// e = (0.6*DL[s] + 0.6*DR[v]) + 0.4*sum_c a_c*|xl[s,c]+xr[v,c]|   (leaky = 0.6t + 0.4|t|)
__global__ __launch_bounds__(256) void k_gat1(const unsigned short* __restrict__ xlr,
                                              const float* __restrict__ dl, const float* __restrict__ dr,
                                              const float* __restrict__ att, const float* __restrict__ bias,
                                              const float* __restrict__ W2l, const float* __restrict__ b2l,
                                              const float* __restrict__ W2r, const float* __restrict__ b2r,
                                              const int* __restrict__ offs, const int* __restrict__ csr,
                                              float* __restrict__ hl, float* __restrict__ hr, int n) {
  int wave = (blockIdx.x * 256 + threadIdx.x) >> 6;
  int lane = threadIdx.x & 63;
  if (wave >= n) return;
  const int v = wave;
  const int g = lane >> 4;   // edge group 0..3
  const int q = lane & 15;   // channel octet: ch q*8 .. q*8+7
  const int cb = q * 8;

  float xrf[8];
  unpack8(*(const uint4*)(xlr + (size_t)v * 256 + 128 + cb), xrf);
  float av[8];
#pragma unroll
  for (int i = 0; i < 8; ++i) av[i] = att[cb + i];
  const float c0 = dr[v];  // 0.6*DR[v], edge-invariant

  float acc[8] = {0.f, 0.f, 0.f, 0.f, 0.f, 0.f, 0.f, 0.f};
  float denom = 0.f;
  const int s0 = offs[v], s1 = offs[v + 1];

  // self-loop (group 0 only)
  if (g == 0) {
    float dls = dl[v];
    float xf[8];
    unpack8(*(const uint4*)(xlr + (size_t)v * 256 + cb), xf);
    float s2 = 0.f;
#pragma unroll
    for (int i = 0; i < 8; ++i) s2 = fmaf(av[i], fabsf(xf[i] + xrf[i]), s2);
    s2 += __shfl_xor(s2, 1, 64);
    s2 += __shfl_xor(s2, 2, 64);
    s2 += __shfl_xor(s2, 4, 64);
    s2 += __shfl_xor(s2, 8, 64);
    float pe = __expf(fmaf(0.4f, s2, dls + c0));
    denom += pe;
#pragma unroll
    for (int i = 0; i < 8; ++i) acc[i] = fmaf(pe, xf[i], acc[i]);
  }

  // main loop: 2 edges in flight per group (j and j+4)
  for (int j = s0 + g; j < s1; j += 8) {
    int jB = j + 4;
    int sA = csr[j];
    bool hB = jB < s1;
    int sB = hB ? csr[jB] : sA;
    float dA = dl[sA];
    float dB = dl[sB];
    float xfA[8], xfB[8];
    unpack8(*(const uint4*)(xlr + (size_t)sA * 256 + cb), xfA);
    unpack8(*(const uint4*)(xlr + (size_t)sB * 256 + cb), xfB);
    float s2A = 0.f, s2B = 0.f;
#pragma unroll
    for (int i = 0; i < 8; ++i) {
      s2A = fmaf(av[i], fabsf(xfA[i] + xrf[i]), s2A);
      s2B = fmaf(av[i], fabsf(xfB[i] + xrf[i]), s2B);
    }
#pragma unroll
    for (int off = 1; off <= 8; off <<= 1) {
      s2A += __shfl_xor(s2A, off, 64);
      s2B += __shfl_xor(s2B, off, 64);
    }
    float peA = __expf(fmaf(0.4f, s2A, dA + c0));
    float peB = hB ? __expf(fmaf(0.4f, s2B, dB + c0)) : 0.f;
    denom += peA + peB;
#pragma unroll
    for (int i = 0; i < 8; ++i)
      acc[i] = fmaf(peB, xfB[i], fmaf(peA, xfA[i], acc[i]));
  }
  // cross-group reduce (xor 16, 32)
#pragma unroll
  for (int off = 16; off <= 32; off <<= 1) {
#pragma unroll
    for (int i = 0; i < 8; ++i) acc[i] += __shfl_xor(acc[i], off, 64);
    denom += __shfl_xor(denom, off, 64);
  }
  float inv = 1.f / denom;
  float pl = 0.f, pr = 0.f;
#pragma unroll
  for (int i = 0; i < 8; ++i) {
    float h = fmaxf(acc[i] * inv + bias[cb + i], 0.f);  // + relu
    pl += h * W2l[cb + i];
    pr += h * W2r[cb + i];
  }
#pragma unroll
  for (int off = 1; off <= 8; off <<= 1) {
    pl += __shfl_xor(pl, off, 64);
    pr += __shfl_xor(pr, off, 64);
  }
  if (lane == 0) {
    hl[v] = pl + b2l[0];
    hr[v] = pr + b2r[0];
  }
}

// ---------------- layer-2 GATv2 (scalar) + sigmoid; self-loop on lane 0 ----------------
__global__ __launch_bounds__(256) void k_gat2(const float* __restrict__ hl, const float* __restrict__ hr,
                                              const float* __restrict__ att2, const float* __restrict__ bias2,
                                              const int* __restrict__ offs, const int* __restrict__ csr,
                                              float* __restrict__ out, int n) {
  int wave = (blockIdx.x * 256 + threadIdx.x) >> 6;
  int lane = threadIdx.x & 63;
  if (wave >= n) return;
  const int v = wave;
  const float a2 = att2[0];
  const float hrv = hr[v];
  float d = 0.f, num = 0.f;
  if (lane == 0) {  // self-loop
    float hlv = hl[v];
    float pe = __expf(a2 * lrelu(hlv + hrv));
    d += pe;
    num += pe * hlv;
  }
  const int s0 = offs[v], s1 = offs[v + 1];
  for (int j = s0 + lane; j < s1; j += 64) {
    int s = csr[j];
    float hls = hl[s];
    float pe = __expf(a2 * lrelu(hls + hrv));
    d += pe;
    num += pe * hls;
  }
#pragma unroll
  for (int off = 32; off; off >>= 1) {
    d += __shfl_xor(d, off, 64);
    num += __shfl_xor(num, off, 64);
  }
  if (lane == 0) {
    float z = num / d + bias2[0];
    float o = 1.f / (1.f + __expf(-z));
    out[v] = o;
    out[n + v] = o;
    out[2 * n + v] = o;
  }
}

extern "C" void kernel_launch(void* const* d_in, const int* in_sizes, int n_in,
                              void* d_out, int out_size, void* d_ws, size_t ws_size,
                              hipStream_t stream) {
  const float* x     = (const float*)d_in[0];
  const int*   ei    = (const int*)d_in[1];
  const float* W1l   = (const float*)d_in[2];
  const float* b1l   = (const float*)d_in[3];
  const float* W1r   = (const float*)d_in[4];
  const float* b1r   = (const float*)d_in[5];
  const float* att1  = (const float*)d_in[6];
  const float* bias1 = (const float*)d_in[7];
  const float* W2l   = (const float*)d_in[8];
  const float* b2l   = (const float*)d_in[9];
  const float* W2r   = (const float*)d_in[10];
  const float* b2r   = (const float*)d_in[11];
  const float* att2  = (const float*)d_in[12];
  const float* bias2 = (const float*)d_in[13];
  float* out = (float*)d_out;

  const int N = in_sizes[0] / 128;
  const int E = in_sizes[1] / 2;
  const int* srcI = ei;
  const int* dstI = ei + E;

  // workspace carve (256-B aligned)
  char* w = (char*)d_ws;
  auto alloc = [&](size_t bytes) {
    char* p = w;
    w += (bytes + 255) & ~(size_t)255;
    return p;
  };
  int* deg   = (int*)alloc((size_t)N * 4);
  int* bsum  = (int*)alloc(1024);
  int* offs  = (int*)alloc((size_t)(N + 1) * 4);
  int* cur   = (int*)alloc((size_t)N * 4);
  int* csr   = (int*)alloc((size_t)E * 4);
  unsigned short* Wth = (unsigned short*)alloc(256 * 128 * 2);
  unsigned short* Wtl = (unsigned short*)alloc(256 * 128 * 2);
  unsigned short* xlr = (unsigned short*)alloc((size_t)N * 256 * 2);
  float* dl  = (float*)alloc((size_t)N * 4);
  float* dr  = (float*)alloc((size_t)N * 4);
  float* hl  = (float*)alloc((size_t)N * 4);
  float* hr  = (float*)alloc((size_t)N * 4);

  const int NB = (N + 255) / 256;
  const float invp = 8.0f / (float)N;

  k_cvtW<<<128, 256, 0, stream>>>(W1l, W1r, Wth, Wtl, deg, N);
  k_hist<<<(E + 255) / 256, 256, 0, stream>>>(dstI, deg, E);
  k_scan1<<<NB, 256, 0, stream>>>(deg, bsum, N);
  k_scan3<<<NB, 256, 0, stream>>>(deg, bsum, offs, cur, N, E, NB);
  k_scatter<<<1024, 256, 0, stream>>>(srcI, dstI, cur, csr, E, invp);

  const int LB = (N + 63) / 64;
  k_mfma<<<LB, 256, 0, stream>>>(x, Wth, Wtl, b1l, b1r, att1, xlr, dl, dr, N);

  const int GB = (N + 3) / 4;  // 4 waves (nodes) per 256-thread block
  k_gat1<<<GB, 256, 0, stream>>>(xlr, dl, dr, att1, bias1, W2l, b2l, W2r, b2r, offs, csr, hl, hr, N);
  k_gat2<<<GB, 256, 0, stream>>>(hl, hr, att2, bias2, offs, csr, out, N);
}